// Round 3
// baseline (119.351 us; speedup 1.0000x reference)
//
#include <hip/hip_runtime.h>
#include <hip/hip_bf16.h>

#define BSZ 4096
#define DIM 512
#define NCLS 64
#define MARGIN_F 1.0f
#define NT 32                      // 128-tiles per dim
#define NPAIR (NT * (NT + 1) / 2)  // 528 upper-tri pair-tiles
#define NBLK (NPAIR * 2)           // each pair-tile split into 2x (64x128)

typedef short short8 __attribute__((ext_vector_type(8)));
typedef float floatx4 __attribute__((ext_vector_type(4)));
typedef unsigned short u16;

// ---------------- workspace layout ----------------
// [0)       : ebf16  BSZ*DIM u16 (4 MiB) normalized bf16 embeddings
// [OFF_POS) : pos_sum BSZ float
// [OFF_NEG) : neg_min BSZ uint (float bits; dist>=0 so bit-order==value-order)
// [OFF_CNT) : int completion counter (fused finalize)
#define OFF_POS  (BSZ * DIM * 2)
#define OFF_NEG  (OFF_POS + BSZ * 4)
#define OFF_CNT  (OFF_NEG + BSZ * 4)

__device__ __forceinline__ u16 f2bf_rne(float f) {
    unsigned x = __float_as_uint(f);
    x += 0x7FFFu + ((x >> 16) & 1u);
    return (u16)(x >> 16);
}

// async global->LDS, 16 B/lane; LDS dest = wave-uniform base + lane*16
__device__ __forceinline__ void gld_lds16(const u16* g, u16* l) {
    __builtin_amdgcn_global_load_lds(
        (const __attribute__((address_space(1))) unsigned int*)g,
        (__attribute__((address_space(3))) unsigned int*)l, 16, 0, 0);
}

// 4 waves/block, one row/wave: L2-normalize, cast bf16, init accums + counter
__global__ __launch_bounds__(256) void ht_normalize(
        const float* __restrict__ emb, u16* __restrict__ ebf,
        float* __restrict__ pos_sum, unsigned* __restrict__ neg_min,
        int* __restrict__ counter) {
    const int lane = threadIdx.x & 63;
    const int row = blockIdx.x * 4 + (threadIdx.x >> 6);
    const float4* r4 = (const float4*)(emb + (size_t)row * DIM);
    float4 v0 = r4[lane * 2];
    float4 v1 = r4[lane * 2 + 1];
    float s = v0.x * v0.x + v0.y * v0.y + v0.z * v0.z + v0.w * v0.w
            + v1.x * v1.x + v1.y * v1.y + v1.z * v1.z + v1.w * v1.w;
#pragma unroll
    for (int off = 1; off < 64; off <<= 1) s += __shfl_xor(s, off);
    const float inv = 1.0f / fmaxf(sqrtf(s), 1e-12f);

    uint4 o;
    o.x = (unsigned)f2bf_rne(v0.x * inv) | ((unsigned)f2bf_rne(v0.y * inv) << 16);
    o.y = (unsigned)f2bf_rne(v0.z * inv) | ((unsigned)f2bf_rne(v0.w * inv) << 16);
    o.z = (unsigned)f2bf_rne(v1.x * inv) | ((unsigned)f2bf_rne(v1.y * inv) << 16);
    o.w = (unsigned)f2bf_rne(v1.z * inv) | ((unsigned)f2bf_rne(v1.w * inv) << 16);
    ((uint4*)(ebf + (size_t)row * DIM))[lane] = o;

    if (lane == 0) { pos_sum[row] = 0.0f; neg_min[row] = 0x7F800000u; }
    if (blockIdx.x == 0 && threadIdx.x == 0) *counter = 0;
}

// 64x128 tile per block (two blocks per upper-tri 128x128 pair-tile).
// 4 waves 2x2 over (rows 64, cols 128): each wave 32x64 via 2x4
// mfma_f32_16x16x32_bf16. Double-buffered LDS, global_load_lds width=16,
// single barrier per k-step: barrier -> issue k+1 -> compute k (load
// latency hidden behind MFMA). Chunk-major LDS [ch][row][8] = conflict-free
// ds_read_b128 AND matches global_load_lds lane fill order.
// Epilogue: row stats always; col stats on off-diagonal pair-tiles.
// Last-finishing block (device acq-rel counter) runs the finalize.
__global__ __launch_bounds__(256, 4) void ht_gemm_reduce(
        const u16* __restrict__ ebf, const int* __restrict__ labels,
        float* __restrict__ pos_sum, unsigned* __restrict__ neg_min,
        int* __restrict__ counter, float* __restrict__ out) {
    __shared__ u16 sA[2][4 * 64 * 8];    // [buf][ch][row][8]
    __shared__ u16 sB[2][4 * 128 * 8];
    __shared__ int sLI[64];              // reused as class hist in finalize
    __shared__ int sLJ[128];
    __shared__ float sT[4];
    __shared__ int sN[4];
    __shared__ int sFlag;

    const int p = blockIdx.x >> 1;       // upper-tri pair index
    const int h = blockIdx.x & 1;        // which 64-row half
    int rem = p, by = 0;
    while (rem >= NT - by) { rem -= NT - by; ++by; }
    const int bx = by + rem;
    const bool offd = (bx != by);

    const int t = threadIdx.x;
    const int row0 = by * 128 + h * 64;
    const int col0 = bx * 128;

    if (t < 64) sLI[t] = labels[row0 + t];
    else if (t < 192) sLJ[t - 64] = labels[col0 + (t - 64)];

    const int lane = t & 63;
    const int wave = t >> 6;
    const int wr = (wave >> 1) * 32;
    const int wc = (wave & 1) * 64;
    const int l15 = lane & 15;
    const int quad = lane >> 4;

    // staging: A 256 segs (1/thread): seg=t -> row=t&63(=lane), ch=t>>6(=wave)
    //          B 512 segs (2/thread): seg=q*256+t -> row=seg&127, ch=seg>>7
    const u16* gA = ebf + (size_t)(row0 + lane) * DIM + wave * 8;
    const u16* gB0 = ebf + (size_t)(col0 + (t & 127)) * DIM + (t >> 7) * 8;
    const u16* gB1 = ebf + (size_t)(col0 + (t & 127)) * DIM + (2 + (t >> 7)) * 8;
    const int lbA = wave * 64 * 8;             // wave-uniform LDS bases (u16)
    const int lbB0 = wave * 64 * 8;
    const int lbB1 = (256 + wave * 64) * 8;

    floatx4 acc[2][4] = {};

    // prologue: stage k=0 into buf 0
    gld_lds16(gA, &sA[0][lbA]);
    gld_lds16(gB0, &sB[0][lbB0]);
    gld_lds16(gB1, &sB[0][lbB1]);

    int cur = 0;
    for (int ks = 0; ks < DIM / 32; ++ks) {
        __syncthreads();  // drains vmcnt: buf[cur] filled; prev reads of buf[cur^1] done
        if (ks + 1 < DIM / 32) {
            const int kb = (ks + 1) * 32;
            gld_lds16(gA + kb, &sA[cur ^ 1][lbA]);
            gld_lds16(gB0 + kb, &sB[cur ^ 1][lbB0]);
            gld_lds16(gB1 + kb, &sB[cur ^ 1][lbB1]);
        }
        short8 af[2], bf[4];
#pragma unroll
        for (int mi = 0; mi < 2; ++mi)
            af[mi] = *(const short8*)(&sA[cur][(quad * 64 + wr + mi * 16 + l15) * 8]);
#pragma unroll
        for (int ni = 0; ni < 4; ++ni)
            bf[ni] = *(const short8*)(&sB[cur][(quad * 128 + wc + ni * 16 + l15) * 8]);
#pragma unroll
        for (int mi = 0; mi < 2; ++mi)
#pragma unroll
            for (int ni = 0; ni < 4; ++ni)
                acc[mi][ni] = __builtin_amdgcn_mfma_f32_16x16x32_bf16(
                    af[mi], bf[ni], acc[mi][ni], 0, 0, 0);
        cur ^= 1;
    }

    // epilogue: C/D layout col=l15, row=quad*4+reg (m89/m91 verified)
    const float INF = __uint_as_float(0x7F800000u);
    float psc[4] = {0.f, 0.f, 0.f, 0.f};
    float nmc[4] = {INF, INF, INF, INF};
#pragma unroll
    for (int mi = 0; mi < 2; ++mi) {
        const int rbase = wr + mi * 16 + quad * 4;
#pragma unroll
        for (int r = 0; r < 4; ++r) {
            const int rloc = rbase + r;
            const int gi = row0 + rloc;
            const int rl = sLI[rloc];
            float ps = 0.0f, nm = INF;
#pragma unroll
            for (int ni = 0; ni < 4; ++ni) {
                const int cloc = wc + ni * 16 + l15;
                const int gj = col0 + cloc;
                const int cl = sLJ[cloc];
                const float d = sqrtf(fmaxf(2.0f - 2.0f * acc[mi][ni][r], 0.0f));
                if (rl == cl) {
                    if (gi != gj) ps += d;      // drop self-pair
                    if (offd) psc[ni] += d;
                } else {
                    nm = fminf(nm, d);
                    if (offd) nmc[ni] = fminf(nmc[ni], d);
                }
            }
#pragma unroll
            for (int off = 1; off < 16; off <<= 1) {
                ps += __shfl_xor(ps, off);
                nm = fminf(nm, __shfl_xor(nm, off));
            }
            if (l15 == 0) {
                if (ps != 0.0f) atomicAdd(&pos_sum[gi], ps);
                atomicMin(&neg_min[gi], __float_as_uint(nm));
            }
        }
    }
    if (offd) {  // column stats: reduce each lane's 32-row partial across quads
#pragma unroll
        for (int ni = 0; ni < 4; ++ni) {
            float ps = psc[ni], nm = nmc[ni];
            ps += __shfl_xor(ps, 16); ps += __shfl_xor(ps, 32);
            nm = fminf(nm, __shfl_xor(nm, 16));
            nm = fminf(nm, __shfl_xor(nm, 32));
            if (quad == 0) {
                const int gj = col0 + wc + ni * 16 + l15;
                if (ps != 0.0f) atomicAdd(&pos_sum[gj], ps);
                atomicMin(&neg_min[gj], __float_as_uint(nm));
            }
        }
    }

    // ---- fused finalize: last-finishing block does it (no spin) ----
    __syncthreads();
    if (t == 0) {
        int old = __hip_atomic_fetch_add(counter, 1, __ATOMIC_ACQ_REL,
                                         __HIP_MEMORY_SCOPE_AGENT);
        sFlag = (old == NBLK - 1);
    }
    __syncthreads();
    if (!sFlag) return;

    if (t < NCLS) sLI[t] = 0;            // reuse sLI as histogram
    __syncthreads();
    for (int i = t; i < BSZ; i += 256) atomicAdd(&sLI[labels[i]], 1);
    __syncthreads();

    float total = 0.0f;
    int nv = 0;
    for (int i = t; i < BSZ; i += 256) {
        const int cnt = sLI[labels[i]];
        const int pc = cnt - 1;
        const int nc = BSZ - cnt;
        if (pc > 0 && nc > 0) {
            const float psv = __hip_atomic_load(&pos_sum[i], __ATOMIC_RELAXED,
                                                __HIP_MEMORY_SCOPE_AGENT);
            const unsigned nmv = __hip_atomic_load(&neg_min[i], __ATOMIC_RELAXED,
                                                   __HIP_MEMORY_SCOPE_AGENT);
            total += fmaxf(psv / (float)pc - __uint_as_float(nmv) + MARGIN_F, 0.0f);
            nv += 1;
        }
    }
#pragma unroll
    for (int off = 1; off < 64; off <<= 1) {
        total += __shfl_xor(total, off);
        nv += __shfl_xor(nv, off);
    }
    if ((t & 63) == 0) { sT[t >> 6] = total; sN[t >> 6] = nv; }
    __syncthreads();
    if (t == 0) {
        const float tt = sT[0] + sT[1] + sT[2] + sT[3];
        const int nn = sN[0] + sN[1] + sN[2] + sN[3];
        out[0] = (nn > 0) ? tt / (float)nn : 0.0f;
    }
}

extern "C" void kernel_launch(void* const* d_in, const int* in_sizes, int n_in,
                              void* d_out, int out_size, void* d_ws, size_t ws_size,
                              hipStream_t stream) {
    const float* emb = (const float*)d_in[0];
    const int* labels = (const int*)d_in[1];
    float* out = (float*)d_out;
    char* ws = (char*)d_ws;

    u16* ebf = (u16*)ws;
    float* pos_sum = (float*)(ws + OFF_POS);
    unsigned* neg_min = (unsigned*)(ws + OFF_NEG);
    int* counter = (int*)(ws + OFF_CNT);

    ht_normalize<<<BSZ / 4, 256, 0, stream>>>(emb, ebf, pos_sum, neg_min, counter);
    ht_gemm_reduce<<<NBLK, 256, 0, stream>>>(ebf, labels, pos_sum, neg_min,
                                             counter, out);
}